// Round 1
// 10995.178 us; speedup vs baseline: 1.4660x; 1.4660x over previous
//
#include <hip/hip_runtime.h>

#define NN 64
#define LDP (NN + 1)  // +1 padding: kills the 32/64-way column-access bank conflicts

// Deflation tolerance: float-storage T has a subdiagonal noise floor of
// ~1.2e-7 * local scale, so 1e-12 would never trigger (forced-deflation
// spiral). 5e-7 is ~4x above the float noise floor; perturbation on
// eigenvalues is ~5e-7*s ~ 1e-5 absolute, well under the 0.03 absmax scale.
#define DEFL_TOL 5e-7

__device__ __forceinline__ double guard_d(double p) {
  if (fabs(p) < 1e-280) return (p >= 0.0) ? 1e-280 : -1e-280;
  return p;
}

// Wave-uniform lane read of a double via v_readlane (no LDS, no lgkmcnt).
__device__ __forceinline__ double readlane_d(double v, int l) {
  union { double d; int i[2]; } u;
  u.d = v;
  int a = __builtin_amdgcn_readlane(u.i[0], l);
  int b = __builtin_amdgcn_readlane(u.i[1], l);
  union { double d; int i[2]; } w;
  w.i[0] = a; w.i[1] = b;
  return w.d;
}

// ============================================================================
// Kernel 1: Hessenberg + Francis double-shift QR -> real Schur.
// T: FLOAT storage in LDS, DOUBLE arithmetic everywhere (same discipline as
// Q: the R4/R5 NaN was float *arithmetic* (float tau=inf, float v=0 ->
// inf*0=NaN on collapsed bulges); storage-only rounding is benign because
// tau/v/beta and the bulge handoff column (cvx/cvy/cvz via readlane) stay in
// double registers and are never rounded through LDS.
// LDS: float Td[64][65] (16640 B) + vbuf (512 B) = 17152 B -> 9 blocks/CU
// (vs 4 with double T). The bulge chase is a pure latency chain (LDS round
// trips + sqrt/div + barriers); 2.25x waves/SIMD is direct latency hiding.
// Outputs: Schur T (float, dense) -> ws slot; Q (float, transposed layout
// Qg[c*64+r] = Q[r][c]) -> out slot (dead until kernel 2's final store).
// ============================================================================
__global__ __launch_bounds__(64) void schur64_kernel(const float* __restrict__ x,
                                                     float* __restrict__ out,
                                                     float* __restrict__ ws) {
  __shared__ float Td[NN][LDP];
  __shared__ double vbuf[NN];

  const int lane = threadIdx.x;
  const size_t mat = blockIdx.x;
  const float* src = x + mat * NN * NN;
  float* Qg = out + mat * NN * NN;  // Q^T layout: Qg[c*64 + r] = Q[r][c]
  float* Tg = ws + mat * NN * NN;   // Schur T handoff to kernel 2

  for (int r = 0; r < NN; ++r) Td[r][lane] = src[r * NN + lane];
  for (int c = 0; c < NN; ++c) Qg[c * NN + lane] = (c == lane) ? 1.0f : 0.0f;
  __syncthreads();

  // ---------------- Hessenberg reduction (float-storage T, double math) ----------------
  for (int k = 0; k <= NN - 3; ++k) {
    const int m = NN - 1 - k;
    double xt = (lane < m) ? (double)Td[k + 1 + lane][k] : 0.0;
    double ss = xt * xt;
    #pragma unroll
    for (int off = 32; off; off >>= 1) ss += __shfl_xor(ss, off);
    double x0 = (double)Td[k + 1][k];
    if (ss > 1e-280) {  // uniform across wave
      double sg = sqrt(ss);
      double beta = (x0 >= 0.0) ? -sg : sg;
      double tau = 1.0 / (ss - beta * x0);
      vbuf[lane] = (lane < m) ? (xt - ((lane == 0) ? beta : 0.0)) : 0.0;
      __syncthreads();
      if (lane >= k + 1) {  // left apply; cols < k structurally zero in rows k+1..
        const int j = lane;
        double acc = 0.0;
        for (int t = 0; t < m; ++t) acc += vbuf[t] * (double)Td[k + 1 + t][j];
        acc *= tau;
        for (int t = 0; t < m; ++t)
          Td[k + 1 + t][j] = (float)((double)Td[k + 1 + t][j] - vbuf[t] * acc);
      }
      __syncthreads();
      if (lane == 0) {  // exact zeros below subdiagonal (col k); disjoint from right apply
        Td[k + 1][k] = (float)beta;
        for (int t = 1; t < m; ++t) Td[k + 1 + t][k] = 0.0f;
      }
      {  // right apply on T cols k+1.. (LDS) and Q cols k+1.. (global, coalesced, DOUBLE math)
        const int r = lane;
        double acc = 0.0;
        double qa = 0.0;
        for (int t = 0; t < m; ++t) {
          double vt = vbuf[t];
          acc += (double)Td[r][k + 1 + t] * vt;
          qa += (double)Qg[(k + 1 + t) * NN + r] * vt;
        }
        acc *= tau;
        qa *= tau;
        for (int t = 0; t < m; ++t) {
          double vt = vbuf[t];
          Td[r][k + 1 + t] = (float)((double)Td[r][k + 1 + t] - acc * vt);
          Qg[(k + 1 + t) * NN + r] =
              (float)((double)Qg[(k + 1 + t) * NN + r] - qa * vt);
        }
      }
      __syncthreads();
    }
  }

  // ---------------- Francis double-shift QR -> real Schur ----------------
  int hi = NN - 1;
  int its = 0, total = 0;
  while (hi > 0) {
    bool small = false;
    if (lane >= 1 && lane <= hi) {
      double s = fabs((double)Td[lane - 1][lane - 1]) + fabs((double)Td[lane][lane]);
      if (s == 0.0) s = 1e-300;
      small = fabs((double)Td[lane][lane - 1]) <= DEFL_TOL * s;
    }
    unsigned long long msk = __ballot(small) | 1ULL;
    if (hi < 63) msk &= (2ULL << hi) - 1ULL;
    const int lo = 63 - __clzll(msk);
    if (lo > 0) {
      __syncthreads();
      if (lane == 0) Td[lo][lo - 1] = 0.0f;
      __syncthreads();
    }
    if (lo == hi) { hi -= 1; its = 0; continue; }
    if (lo == hi - 1) {  // 2x2 window
      double a = Td[hi - 1][hi - 1], b = Td[hi - 1][hi];
      double c = Td[hi][hi - 1], d = Td[hi][hi];
      double pp = 0.5 * (a - d);
      double disc = pp * pp + b * c;
      if (disc >= 0.0) {  // real pair: rotate to triangular
        double sq = sqrt(disc);
        double mid = 0.5 * (a + d);
        double lam = mid + ((mid >= 0.0) ? sq : -sq);
        double u0 = b, u1 = lam - a;
        double w0 = lam - d, w1 = c;
        double nu = u0 * u0 + u1 * u1, nw = w0 * w0 + w1 * w1;
        double cs, sn;
        if (nu >= nw && nu > 1e-280) { double n2 = sqrt(nu); cs = u0 / n2; sn = u1 / n2; }
        else if (nw > 1e-280) { double n2 = sqrt(nw); cs = w0 / n2; sn = w1 / n2; }
        else { cs = 1.0; sn = 0.0; }
        {
          const int j = lane;
          double r0 = Td[hi - 1][j], r1 = Td[hi][j];
          Td[hi - 1][j] = (float)(cs * r0 + sn * r1);
          Td[hi][j] = (float)(cs * r1 - sn * r0);
        }
        __syncthreads();
        {
          const int r = lane;
          double c0 = Td[r][hi - 1], c1 = Td[r][hi];
          Td[r][hi - 1] = (float)(cs * c0 + sn * c1);
          Td[r][hi] = (float)(cs * c1 - sn * c0);
          double q0 = (double)Qg[(hi - 1) * NN + r], q1 = (double)Qg[hi * NN + r];
          Qg[(hi - 1) * NN + r] = (float)(cs * q0 + sn * q1);
          Qg[hi * NN + r] = (float)(cs * q1 - sn * q0);
        }
        __syncthreads();
        if (lane == 0) Td[hi][hi - 1] = 0.0f;
        __syncthreads();
      }
      hi -= 2; its = 0; continue;
    }
    ++its; ++total;
    if (its > 40 || total > 2000) {  // safety: force deflation
      __syncthreads();
      if (lane == 0) Td[hi][hi - 1] = 0.0f;
      __syncthreads();
      hi -= 1; its = 0; continue;
    }
    double sa, sb, sc2, sd2;
    if (its == 10 || its == 20 || its == 30) {  // exceptional shift (dlahqr style)
      double sx = fabs((double)Td[hi][hi - 1]) + fabs((double)Td[hi - 1][hi - 2]);
      sa = 0.75 * sx + (double)Td[hi][hi]; sb = -0.4375 * sx; sc2 = sx; sd2 = sa;
    } else {
      sa = Td[hi - 1][hi - 1]; sb = Td[hi - 1][hi];
      sc2 = Td[hi][hi - 1]; sd2 = Td[hi][hi];
    }
    double tr = sa + sd2;
    double det = sa * sd2 - sb * sc2;
    double h11 = Td[lo][lo], h12 = Td[lo][lo + 1], h21 = Td[lo + 1][lo];
    double h22 = Td[lo + 1][lo + 1], h32 = Td[lo + 2][lo + 1];
    double cvx = h11 * h11 + h12 * h21 - tr * h11 + det;
    double cvy = h21 * (h11 + h22 - tr);
    double cvz = h21 * h32;
    // Q 3-column register window (cols k..k+2); DOUBLE registers, float storage
    double qw0 = (double)Qg[lo * NN + lane];
    double qw1 = (double)Qg[(lo + 1) * NN + lane];
    double qw2 = (double)Qg[(lo + 2) * NN + lane];
    bool broke = false;
    for (int k = lo; k <= hi - 1; ++k) {  // bulge chase
      const int nr = (k + 2 <= hi) ? 3 : 2;
      const double vx = cvx, vy = cvy, vz = (nr == 3) ? cvz : 0.0;
      double ss2 = vx * vx + vy * vy + vz * vz;
      if (ss2 < 1e-280) {  // bulge collapsed; flush pending window cols
        Qg[k * NN + lane] = (float)qw0;
        Qg[(k + 1) * NN + lane] = (float)qw1;
        if (k + 2 <= hi) Qg[(k + 2) * NN + lane] = (float)qw2;
        broke = true; break;
      }
      double sg = sqrt(ss2);
      double beta = (vx >= 0.0) ? -sg : sg;
      double v0 = vx - beta, v1 = vy, v2 = vz;
      double tau = 1.0 / (ss2 - beta * vx);
      double qnext = 0.0;
      if (k + 3 <= hi) qnext = (double)Qg[(k + 3) * NN + lane];  // prefetch next window col
      const int jlo = (k > lo) ? k : lo;
      if (lane >= jlo) {  // left apply
        const int j = lane;
        double t0 = Td[k][j], t1 = Td[k + 1][j];
        double t2v = (nr == 3) ? (double)Td[k + 2][j] : 0.0;
        double tt = tau * (v0 * t0 + v1 * t1 + v2 * t2v);
        Td[k][j] = (float)(t0 - v0 * tt);
        Td[k + 1][j] = (float)(t1 - v1 * tt);
        if (nr == 3) Td[k + 2][j] = (float)(t2v - v2 * tt);
      }
      __syncthreads();
      if (lane == 0 && k > lo) {  // exact bulge zeros (col k-1)
        Td[k][k - 1] = (float)beta;
        Td[k + 1][k - 1] = 0.0f;
        if (nr == 3) Td[k + 2][k - 1] = 0.0f;
      }
      const int rmax = (k + 3 <= hi) ? (k + 3) : hi;
      double n0 = 0.0, n1 = 0.0, n2 = 0.0;
      if (lane <= rmax) {  // right apply on T (rows below are structurally zero)
        double c0 = Td[lane][k], c1 = Td[lane][k + 1];
        double c2v = (nr == 3) ? (double)Td[lane][k + 2] : 0.0;
        double tt = tau * (c0 * v0 + c1 * v1 + c2v * v2);
        n0 = c0 - tt * v0;
        n1 = c1 - tt * v1;
        n2 = c2v - tt * v2;
      }
      {  // register handoff of next bulge column before LDS writes (stays DOUBLE:
         // the bulge-generating column is never rounded through float storage)
        const int ly = (k + 2 <= 63) ? (k + 2) : 0;
        const int lz = (k + 3 <= hi) ? (k + 3) : 0;
        cvx = readlane_d(n0, k + 1);
        cvy = readlane_d(n0, ly);
        cvz = readlane_d(n0, lz);
      }
      if (lane <= rmax) {
        Td[lane][k] = (float)n0;
        Td[lane][k + 1] = (float)n1;
        if (nr == 3) Td[lane][k + 2] = (float)n2;
      }
      {  // Q window update — DOUBLE math (scale-safe for collapsed bulges)
        double tq = tau * (qw0 * v0 + qw1 * v1 + ((nr == 3) ? qw2 * v2 : 0.0));
        qw0 -= tq * v0;
        qw1 -= tq * v1;
        if (nr == 3) qw2 -= tq * v2;
      }
      Qg[k * NN + lane] = (float)qw0;  // col k final for this sweep
      qw0 = qw1; qw1 = qw2; qw2 = qnext;
      __syncthreads();
    }
    if (!broke) Qg[hi * NN + lane] = (float)qw0;  // flush last window col
  }
  __syncthreads();

  // ---------------- write Schur T to workspace (coalesced) ----------------
  for (int r = 0; r < NN; ++r) Tg[r * NN + lane] = Td[r][lane];
}

// ============================================================================
// Kernel 2: Parlett recurrence (F = |.| on spectrum) + symmetrize + Q F Q^T.
// Structure identical to the proven tail of the single-kernel version (that
// code already ran Parlett on FLOAT T after the in-place conversion); here T
// arrives as float from ws. LDS: Tf + F (2 x 16640 B) = 33280 B -> 4 blocks/
// CU — fine, this is the minor phase.
// ============================================================================
__global__ __launch_bounds__(64) void parlett64_kernel(const float* __restrict__ ws,
                                                       float* __restrict__ out) {
  __shared__ float Tfbuf[NN * LDP];
  __shared__ float Fbuf[NN * LDP];
  float* Tf = Tfbuf;
  float* Fp = Fbuf;

  const int lane = threadIdx.x;
  const size_t mat = blockIdx.x;
  const float* Tg = ws + mat * NN * NN;
  float* dst = out + mat * NN * NN;
  float* Qg = dst;  // holds Q^T layout from kernel 1; dead after LDS staging

  #define TF(r, c) ((double)Tf[(r) * LDP + (c)])
  #define FF(r, c) Fp[(r) * LDP + (c)]

  for (int r = 0; r < NN; ++r) Tf[r * LDP + lane] = Tg[r * NN + lane];
  __syncthreads();

  // ---------------- block structure + diag f-values ----------------
  unsigned long long pair_mask =
      __ballot((lane < NN - 1) && (Tf[(lane + 1) * LDP + lane] != 0.0f));
  unsigned long long start_mask = ~(pair_mask << 1);  // bit p set iff block starts at p
  const bool isstart = (start_mask >> lane) & 1ULL;
  const bool ispair = (pair_mask >> lane) & 1ULL;
  double fdiag = 0.0, mymod = 1e300;
  if (isstart) {
    if (ispair) {  // complex pair: |lambda| = sqrt(det)
      double a = TF(lane, lane), b = TF(lane, lane + 1);
      double c = TF(lane + 1, lane), d = TF(lane + 1, lane + 1);
      fdiag = sqrt(fmax(a * d - b * c, 0.0));
    } else {
      fdiag = fabs(TF(lane, lane));
    }
    mymod = fdiag;
  }
  #pragma unroll
  for (int off = 32; off; off >>= 1) mymod = fmin(mymod, __shfl_xor(mymod, off));
  const double cshift = 1e-6 * mymod;

  for (int r = 0; r < NN; ++r) FF(r, lane) = 0.0f;
  __syncthreads();
  if (isstart) {
    FF(lane, lane) = (float)fdiag;
    if (ispair) FF(lane + 1, lane + 1) = (float)fdiag;
  }
  __syncthreads();

  // ---------------- Parlett recurrence: F = f(T), f = |.| on spectrum ----------------
  for (int dist = 1; dist < NN; ++dist) {
    const int si = lane, sj = lane + dist;
    bool active = (sj < NN) && ((start_mask >> si) & 1ULL) && ((start_mask >> sj) & 1ULL);
    if (active) {
      const int p = ((pair_mask >> si) & 1ULL) ? 2 : 1;
      const int q = ((pair_mask >> sj) & 1ULL) ? 2 : 1;
      double c00 = 0, c01 = 0, c10 = 0, c11 = 0;
      int k = si;
      while (k < sj) {
        const bool kp = (pair_mask >> k) & 1ULL;
        double f00 = FF(si, k);
        double f01 = kp ? (double)FF(si, k + 1) : 0.0;
        double f10 = (p == 2) ? (double)FF(si + 1, k) : 0.0;
        double f11 = (p == 2 && kp) ? (double)FF(si + 1, k + 1) : 0.0;
        double t00 = TF(k, sj);
        double t01 = (q == 2) ? TF(k, sj + 1) : 0.0;
        double t10 = kp ? TF(k + 1, sj) : 0.0;
        double t11 = (kp && q == 2) ? TF(k + 1, sj + 1) : 0.0;
        c00 += f00 * t00 + f01 * t10;
        c01 += f00 * t01 + f01 * t11;
        c10 += f10 * t00 + f11 * t10;
        c11 += f10 * t01 + f11 * t11;
        k += kp ? 2 : 1;
      }
      k = si + p;
      while (k <= sj) {
        const bool kp = (pair_mask >> k) & 1ULL;
        double t00 = TF(si, k);
        double t01 = kp ? TF(si, k + 1) : 0.0;
        double t10 = (p == 2) ? TF(si + 1, k) : 0.0;
        double t11 = (p == 2 && kp) ? TF(si + 1, k + 1) : 0.0;
        double f00 = FF(k, sj);
        double f01 = (q == 2) ? (double)FF(k, sj + 1) : 0.0;
        double f10 = kp ? (double)FF(k + 1, sj) : 0.0;
        double f11 = (kp && q == 2) ? (double)FF(k + 1, sj + 1) : 0.0;
        c00 -= t00 * f00 + t01 * f10;
        c01 -= t00 * f01 + t01 * f11;
        c10 -= t10 * f00 + t11 * f10;
        c11 -= t10 * f01 + t11 * f11;
        k += kp ? 2 : 1;
      }
      // solve T_ii X - X T_jj = C
      double x00 = 0, x01 = 0, x10 = 0, x11 = 0;
      if (p == 1 && q == 1) {
        x00 = c00 / guard_d(TF(si, si) - TF(sj, sj));
      } else if (p == 2 && q == 1) {
        double t = TF(sj, sj);
        double m00 = TF(si, si) - t, m01 = TF(si, si + 1);
        double m10 = TF(si + 1, si), m11 = TF(si + 1, si + 1) - t;
        double dd = guard_d(m00 * m11 - m01 * m10);
        x00 = (m11 * c00 - m01 * c10) / dd;
        x10 = (m00 * c10 - m10 * c00) / dd;
      } else if (p == 1 && q == 2) {
        double t = TF(si, si);
        double m00 = t - TF(sj, sj), m01 = -TF(sj, sj + 1);
        double m10 = -TF(sj + 1, sj), m11 = t - TF(sj + 1, sj + 1);
        double dd = guard_d(m00 * m11 - m01 * m10);
        x00 = (c00 * m11 - c01 * m10) / dd;
        x01 = (c01 * m00 - c00 * m01) / dd;
      } else {
        double A00 = TF(si, si), A01 = TF(si, si + 1);
        double A10 = TF(si + 1, si), A11 = TF(si + 1, si + 1);
        double B00 = TF(sj, sj), B01 = TF(sj, sj + 1);
        double B10 = TF(sj + 1, sj), B11 = TF(sj + 1, sj + 1);
        double M[4][5] = {
            {A00 - B00, A01, -B10, 0.0, c00},
            {A10, A11 - B00, 0.0, -B10, c10},
            {-B01, 0.0, A00 - B11, A01, c01},
            {0.0, -B01, A10, A11 - B11, c11}};
        #pragma unroll
        for (int cc = 0; cc < 4; ++cc) {
          #pragma unroll
          for (int rr2 = cc + 1; rr2 < 4; ++rr2) {  // bubble-max partial pivot
            bool sw = fabs(M[rr2][cc]) > fabs(M[cc][cc]);
            #pragma unroll
            for (int t2 = cc; t2 < 5; ++t2) {
              double aa = M[cc][t2], bb = M[rr2][t2];
              M[cc][t2] = sw ? bb : aa;
              M[rr2][t2] = sw ? aa : bb;
            }
          }
          double inv = 1.0 / guard_d(M[cc][cc]);
          #pragma unroll
          for (int rr2 = cc + 1; rr2 < 4; ++rr2) {
            double f2 = M[rr2][cc] * inv;
            #pragma unroll
            for (int t2 = cc; t2 < 5; ++t2) M[rr2][t2] -= f2 * M[cc][t2];
          }
        }
        double z3 = M[3][4] / guard_d(M[3][3]);
        double z2 = (M[2][4] - M[2][3] * z3) / guard_d(M[2][2]);
        double z1 = (M[1][4] - M[1][3] * z3 - M[1][2] * z2) / guard_d(M[1][1]);
        double z0 = (M[0][4] - M[0][3] * z3 - M[0][2] * z2 - M[0][1] * z1) / guard_d(M[0][0]);
        x00 = z0; x10 = z1; x01 = z2; x11 = z3;
      }
      FF(si, sj) = (float)x00;
      if (q == 2) FF(si, sj + 1) = (float)x01;
      if (p == 2) {
        FF(si + 1, sj) = (float)x10;
        if (q == 2) FF(si + 1, sj + 1) = (float)x11;
      }
    }
    __syncthreads();
  }

  // ---------------- symmetrize + eps shift ----------------
  {
    const int r = lane;
    for (int j = r + 1; j < NN; ++j) {
      float v = 0.5f * (FF(r, j) + FF(j, r));
      FF(r, j) = v;
      FF(j, r) = v;
    }
    FF(r, r) += (float)cshift;
  }
  __syncthreads();

  // ---------------- stage Q into dead T region; out = Q Fs Q^T ----------------
  float* Qs = Tf;  // T dead after Parlett
  for (int c = 0; c < NN; ++c) Qs[lane * LDP + c] = Qg[c * NN + lane];
  __syncthreads();

  float acc[NN];
  #pragma unroll
  for (int i = 0; i < NN; ++i) acc[i] = 0.0f;
  for (int k = 0; k < NN; ++k) {  // W = Q * Fs ; lane = column j
    float f = FF(k, lane);
    #pragma unroll
    for (int i = 0; i < NN; ++i) acc[i] += Qs[i * LDP + k] * f;
  }
  __syncthreads();  // all Fs reads done before W overwrites the region
  float* W = Fp;    // F dead after GEMM1
  #pragma unroll
  for (int i = 0; i < NN; ++i) W[i * LDP + lane] = acc[i];
  __syncthreads();

  #pragma unroll
  for (int i = 0; i < NN; ++i) acc[i] = 0.0f;
  for (int k = 0; k < NN; ++k) {  // out = W * Q^T ; lane = column j
    float qv = Qs[lane * LDP + k];
    #pragma unroll
    for (int i = 0; i < NN; ++i) acc[i] += W[i * LDP + k] * qv;
  }
  #pragma unroll
  for (int i = 0; i < NN; ++i) dst[i * NN + lane] = acc[i];

  #undef TF
  #undef FF
}

extern "C" void kernel_launch(void* const* d_in, const int* in_sizes, int n_in,
                              void* d_out, int out_size, void* d_ws, size_t ws_size,
                              hipStream_t stream) {
  const float* x = (const float*)d_in[0];
  float* out = (float*)d_out;
  float* ws = (float*)d_ws;  // needs nmat*64*64*4 B = 64 MB for Schur T handoff
  const int nmat = in_sizes[0] / (NN * NN);  // 4096
  schur64_kernel<<<nmat, 64, 0, stream>>>(x, out, ws);
  parlett64_kernel<<<nmat, 64, 0, stream>>>(ws, out);
}

// Round 2
// 8005.424 us; speedup vs baseline: 2.0135x; 1.3735x over previous
//
#include <hip/hip_runtime.h>

#define NN 64
#define LDP (NN + 1)  // +1 padding: kills the 32/64-way column-access bank conflicts

// Deflation tolerance: float-storage T has a subdiagonal noise floor of
// ~1.2e-7 * local scale; 5e-7 is ~4x above it (proven R1: passed, absmax
// unchanged at 0.03125).
#define DEFL_TOL 5e-7

// Packed upper-Hessenberg band with 3 subdiagonals (bulge reaches exactly
// row-col = 3: the (k+2, k-1) zero write). Row r stores cols max(0,r-3)..63.
// Total = 2266 floats = 9064 B -> ~17 blocks/CU (vs 9 for dense 64x65).
#define BAND_SIZE 2266

__device__ __forceinline__ int rb_of(int r) {
  // TD(r,c) == band[rb_of(r) + c], valid for c in [max(0,r-3), 63].
  // rowoff(r) = 64r - sum_{s<r} max(0,s-3); rb = rowoff - max(0,r-3).
  int t = (r >= 4) ? (((r - 4) * (r - 3)) >> 1) : 0;
  int s = (r >= 3) ? (r - 3) : 0;
  return 64 * r - t - s;
}

__device__ __forceinline__ double guard_d(double p) {
  if (fabs(p) < 1e-280) return (p >= 0.0) ? 1e-280 : -1e-280;
  return p;
}

// Wave-uniform lane read of a double via v_readlane (no LDS, no lgkmcnt).
__device__ __forceinline__ double readlane_d(double v, int l) {
  union { double d; int i[2]; } u;
  u.d = v;
  int a = __builtin_amdgcn_readlane(u.i[0], l);
  int b = __builtin_amdgcn_readlane(u.i[1], l);
  union { double d; int i[2]; } w;
  w.i[0] = a; w.i[1] = b;
  return w.d;
}

// ============================================================================
// Kernel 1: Hessenberg reduction. FLOAT-storage T in LDS, DOUBLE math (R1-
// proven). Q (float, transposed layout Qg[c*64+r]=Q[r][c]) built in d_out.
// Writes dense Hessenberg H -> ws. LDS 17152 B -> 9 blocks/CU.
// ============================================================================
__global__ __launch_bounds__(64) void hess64_kernel(const float* __restrict__ x,
                                                    float* __restrict__ out,
                                                    float* __restrict__ ws) {
  __shared__ float Td[NN][LDP];
  __shared__ double vbuf[NN];

  const int lane = threadIdx.x;
  const size_t mat = blockIdx.x;
  const float* src = x + mat * NN * NN;
  float* Qg = out + mat * NN * NN;
  float* Tg = ws + mat * NN * NN;

  for (int r = 0; r < NN; ++r) Td[r][lane] = src[r * NN + lane];
  for (int c = 0; c < NN; ++c) Qg[c * NN + lane] = (c == lane) ? 1.0f : 0.0f;
  __syncthreads();

  for (int k = 0; k <= NN - 3; ++k) {
    const int m = NN - 1 - k;
    double xt = (lane < m) ? (double)Td[k + 1 + lane][k] : 0.0;
    double ss = xt * xt;
    #pragma unroll
    for (int off = 32; off; off >>= 1) ss += __shfl_xor(ss, off);
    double x0 = (double)Td[k + 1][k];
    if (ss > 1e-280) {  // uniform across wave
      double sg = sqrt(ss);
      double beta = (x0 >= 0.0) ? -sg : sg;
      double tau = 1.0 / (ss - beta * x0);
      vbuf[lane] = (lane < m) ? (xt - ((lane == 0) ? beta : 0.0)) : 0.0;
      __syncthreads();
      if (lane >= k + 1) {  // left apply
        const int j = lane;
        double acc = 0.0;
        for (int t = 0; t < m; ++t) acc += vbuf[t] * (double)Td[k + 1 + t][j];
        acc *= tau;
        for (int t = 0; t < m; ++t)
          Td[k + 1 + t][j] = (float)((double)Td[k + 1 + t][j] - vbuf[t] * acc);
      }
      __syncthreads();
      if (lane == 0) {  // exact zeros below subdiagonal (col k)
        Td[k + 1][k] = (float)beta;
        for (int t = 1; t < m; ++t) Td[k + 1 + t][k] = 0.0f;
      }
      {  // right apply on T (LDS) and Q (global, coalesced, DOUBLE math)
        const int r = lane;
        double acc = 0.0;
        double qa = 0.0;
        for (int t = 0; t < m; ++t) {
          double vt = vbuf[t];
          acc += (double)Td[r][k + 1 + t] * vt;
          qa += (double)Qg[(k + 1 + t) * NN + r] * vt;
        }
        acc *= tau;
        qa *= tau;
        for (int t = 0; t < m; ++t) {
          double vt = vbuf[t];
          Td[r][k + 1 + t] = (float)((double)Td[r][k + 1 + t] - acc * vt);
          Qg[(k + 1 + t) * NN + r] =
              (float)((double)Qg[(k + 1 + t) * NN + r] - qa * vt);
        }
      }
      __syncthreads();
    }
  }

  for (int r = 0; r < NN; ++r) Tg[r * NN + lane] = Td[r][lane];
}

// ============================================================================
// Kernel 2: Francis double-shift QR on PACKED BAND storage (the dominant,
// serial-latency phase -> max occupancy: 9.1 KB LDS -> ~17 blocks/CU = 4.25
// waves/SIMD vs 2.25 before). Math identical to the R1-proven dense version;
// only the T addressing changed (TD macro). New guards only in the 2x2
// rotations where the dense code touched exact-zero out-of-band entries.
// ============================================================================
#define TD(r, c) band[rb_of(r) + (c)]

__global__ __launch_bounds__(64) void qr64_kernel(float* __restrict__ out,
                                                  float* __restrict__ ws) {
  __shared__ float band[BAND_SIZE];

  const int lane = threadIdx.x;
  const size_t mat = blockIdx.x;
  float* Qg = out + mat * NN * NN;
  float* Tg = ws + mat * NN * NN;

  // dense H -> band (cols >= max(0,r-3); includes H's exact zeros at r-2,r-3)
  for (int r = 0; r < NN; ++r) {
    int st = (r >= 3) ? (r - 3) : 0;
    if (lane >= st) band[rb_of(r) + lane] = Tg[r * NN + lane];
  }
  __syncthreads();

  int hi = NN - 1;
  int its = 0, total = 0;
  while (hi > 0) {
    bool small = false;
    if (lane >= 1 && lane <= hi) {
      double s = fabs((double)TD(lane - 1, lane - 1)) + fabs((double)TD(lane, lane));
      if (s == 0.0) s = 1e-300;
      small = fabs((double)TD(lane, lane - 1)) <= DEFL_TOL * s;
    }
    unsigned long long msk = __ballot(small) | 1ULL;
    if (hi < 63) msk &= (2ULL << hi) - 1ULL;
    const int lo = 63 - __clzll(msk);
    if (lo > 0) {
      __syncthreads();
      if (lane == 0) TD(lo, lo - 1) = 0.0f;
      __syncthreads();
    }
    if (lo == hi) { hi -= 1; its = 0; continue; }
    if (lo == hi - 1) {  // 2x2 window
      double a = TD(hi - 1, hi - 1), b = TD(hi - 1, hi);
      double c = TD(hi, hi - 1), d = TD(hi, hi);
      double pp = 0.5 * (a - d);
      double disc = pp * pp + b * c;
      if (disc >= 0.0) {  // real pair: rotate to triangular
        double sq = sqrt(disc);
        double mid = 0.5 * (a + d);
        double lam = mid + ((mid >= 0.0) ? sq : -sq);
        double u0 = b, u1 = lam - a;
        double w0 = lam - d, w1 = c;
        double nu = u0 * u0 + u1 * u1, nw = w0 * w0 + w1 * w1;
        double cs, sn;
        if (nu >= nw && nu > 1e-280) { double n2 = sqrt(nu); cs = u0 / n2; sn = u1 / n2; }
        else if (nw > 1e-280) { double n2 = sqrt(nw); cs = w0 / n2; sn = w1 / n2; }
        else { cs = 1.0; sn = 0.0; }
        {
          const int j = lane;
          const int jmin = (hi >= 2) ? (hi - 2) : 0;  // cols < hi-2 are exact 0 in both rows
          if (j >= jmin) {
            double r0 = TD(hi - 1, j), r1 = TD(hi, j);
            TD(hi - 1, j) = (float)(cs * r0 + sn * r1);
            TD(hi, j) = (float)(cs * r1 - sn * r0);
          }
        }
        __syncthreads();
        {
          const int r = lane;
          if (r <= hi) {  // rows > hi are exact 0 in cols hi-1,hi (and out-of-band)
            double c0 = TD(r, hi - 1), c1 = TD(r, hi);
            TD(r, hi - 1) = (float)(cs * c0 + sn * c1);
            TD(r, hi) = (float)(cs * c1 - sn * c0);
          }
          double q0 = (double)Qg[(hi - 1) * NN + r], q1 = (double)Qg[hi * NN + r];
          Qg[(hi - 1) * NN + r] = (float)(cs * q0 + sn * q1);
          Qg[hi * NN + r] = (float)(cs * q1 - sn * q0);
        }
        __syncthreads();
        if (lane == 0) TD(hi, hi - 1) = 0.0f;
        __syncthreads();
      }
      hi -= 2; its = 0; continue;
    }
    ++its; ++total;
    if (its > 40 || total > 2000) {  // safety: force deflation
      __syncthreads();
      if (lane == 0) TD(hi, hi - 1) = 0.0f;
      __syncthreads();
      hi -= 1; its = 0; continue;
    }
    double sa, sb, sc2, sd2;
    if (its == 10 || its == 20 || its == 30) {  // exceptional shift (dlahqr style)
      double sx = fabs((double)TD(hi, hi - 1)) + fabs((double)TD(hi - 1, hi - 2));
      sa = 0.75 * sx + (double)TD(hi, hi); sb = -0.4375 * sx; sc2 = sx; sd2 = sa;
    } else {
      sa = TD(hi - 1, hi - 1); sb = TD(hi - 1, hi);
      sc2 = TD(hi, hi - 1); sd2 = TD(hi, hi);
    }
    double tr = sa + sd2;
    double det = sa * sd2 - sb * sc2;
    double h11 = TD(lo, lo), h12 = TD(lo, lo + 1), h21 = TD(lo + 1, lo);
    double h22 = TD(lo + 1, lo + 1), h32 = TD(lo + 2, lo + 1);
    double cvx = h11 * h11 + h12 * h21 - tr * h11 + det;
    double cvy = h21 * (h11 + h22 - tr);
    double cvz = h21 * h32;
    // Q 3-column register window; DOUBLE registers, float storage
    double qw0 = (double)Qg[lo * NN + lane];
    double qw1 = (double)Qg[(lo + 1) * NN + lane];
    double qw2 = (double)Qg[(lo + 2) * NN + lane];
    bool broke = false;
    for (int k = lo; k <= hi - 1; ++k) {  // bulge chase
      const int nr = (k + 2 <= hi) ? 3 : 2;
      const double vx = cvx, vy = cvy, vz = (nr == 3) ? cvz : 0.0;
      double ss2 = vx * vx + vy * vy + vz * vz;
      if (ss2 < 1e-280) {  // bulge collapsed; flush pending window cols
        Qg[k * NN + lane] = (float)qw0;
        Qg[(k + 1) * NN + lane] = (float)qw1;
        if (k + 2 <= hi) Qg[(k + 2) * NN + lane] = (float)qw2;
        broke = true; break;
      }
      double sg = sqrt(ss2);
      double beta = (vx >= 0.0) ? -sg : sg;
      double v0 = vx - beta, v1 = vy, v2 = vz;
      double tau = 1.0 / (ss2 - beta * vx);
      double qnext = 0.0;
      if (k + 3 <= hi) qnext = (double)Qg[(k + 3) * NN + lane];  // prefetch
      const int jlo = (k > lo) ? k : lo;
      if (lane >= jlo) {  // left apply (rows k..k+2, cols >= k: in-band)
        const int j = lane;
        double t0 = TD(k, j), t1 = TD(k + 1, j);
        double t2v = (nr == 3) ? (double)TD(k + 2, j) : 0.0;
        double tt = tau * (v0 * t0 + v1 * t1 + v2 * t2v);
        TD(k, j) = (float)(t0 - v0 * tt);
        TD(k + 1, j) = (float)(t1 - v1 * tt);
        if (nr == 3) TD(k + 2, j) = (float)(t2v - v2 * tt);
      }
      __syncthreads();
      if (lane == 0 && k > lo) {  // exact bulge zeros (col k-1; diff <= 3: in-band)
        TD(k, k - 1) = (float)beta;
        TD(k + 1, k - 1) = 0.0f;
        if (nr == 3) TD(k + 2, k - 1) = 0.0f;
      }
      const int rmax = (k + 3 <= hi) ? (k + 3) : hi;
      double n0 = 0.0, n1 = 0.0, n2 = 0.0;
      if (lane <= rmax) {  // right apply (rows <= k+3, cols k..k+2: in-band)
        double c0 = TD(lane, k), c1 = TD(lane, k + 1);
        double c2v = (nr == 3) ? (double)TD(lane, k + 2) : 0.0;
        double tt = tau * (c0 * v0 + c1 * v1 + c2v * v2);
        n0 = c0 - tt * v0;
        n1 = c1 - tt * v1;
        n2 = c2v - tt * v2;
      }
      {  // register handoff of next bulge column (DOUBLE, never rounded)
        const int ly = (k + 2 <= 63) ? (k + 2) : 0;
        const int lz = (k + 3 <= hi) ? (k + 3) : 0;
        cvx = readlane_d(n0, k + 1);
        cvy = readlane_d(n0, ly);
        cvz = readlane_d(n0, lz);
      }
      if (lane <= rmax) {
        TD(lane, k) = (float)n0;
        TD(lane, k + 1) = (float)n1;
        if (nr == 3) TD(lane, k + 2) = (float)n2;
      }
      {  // Q window update — DOUBLE math
        double tq = tau * (qw0 * v0 + qw1 * v1 + ((nr == 3) ? qw2 * v2 : 0.0));
        qw0 -= tq * v0;
        qw1 -= tq * v1;
        if (nr == 3) qw2 -= tq * v2;
      }
      Qg[k * NN + lane] = (float)qw0;  // col k final for this sweep
      qw0 = qw1; qw1 = qw2; qw2 = qnext;
      __syncthreads();
    }
    if (!broke) Qg[hi * NN + lane] = (float)qw0;  // flush last window col
  }
  __syncthreads();

  // band -> dense Schur T (subdiag + upper only; sub-sub remnants dropped,
  // matching what parlett consumes)
  for (int r = 0; r < NN; ++r) {
    float v = 0.0f;
    int st = (r >= 1) ? (r - 1) : 0;
    if (lane >= st) v = band[rb_of(r) + lane];
    Tg[r * NN + lane] = v;
  }
}

// ============================================================================
// Kernel 3: Parlett recurrence + symmetrize + Q Fs Q^T. Now 256 threads:
// each Sylvester pair (si, si+dist) is handled by a 4-thread group (pairs
// striped across waves by si&3 so active pairs stay balanced), splitting the
// k-sum 4-way with a shfl_xor(1,2) reduce. The data-dependent k-walk
// (k += kp?2:1) is replaced by a precomputed block-start table so the loop
// pipelines. LDS 33.8 KB -> 4 blocks/CU x 4 waves = 16 waves/CU (vs 4).
// Numerics: identical values; only the double k-sums are re-associated.
// ============================================================================
__global__ __launch_bounds__(256) void parlett64_kernel(const float* __restrict__ ws,
                                                        float* __restrict__ out) {
  __shared__ float Tfbuf[NN * LDP];
  __shared__ float Fbuf[NN * LDP];
  __shared__ int blkstart[NN];  // block ordinal -> start position
  __shared__ int bi_of[NN];     // start position -> block ordinal
  float* Tf = Tfbuf;
  float* Fp = Fbuf;

  const int tid = threadIdx.x;
  const int w = tid >> 6;     // wave 0..3
  const int lane = tid & 63;  // lane within wave
  const size_t mat = blockIdx.x;
  const float* Tg = ws + mat * NN * NN;
  float* dst = out + mat * NN * NN;
  float* Qg = dst;  // Q^T layout from kernel 1/2; dead after LDS staging

  #define TF(r, c) ((double)Tf[(r) * LDP + (c)])
  #define FF(r, c) Fp[(r) * LDP + (c)]

  for (int r = w; r < NN; r += 4) Tf[r * LDP + lane] = Tg[r * NN + lane];
  __syncthreads();

  // block structure: per-wave identical (same LDS data -> same ballot)
  unsigned long long pair_mask =
      __ballot((lane < NN - 1) && (Tf[(lane + 1) * LDP + lane] != 0.0f));
  unsigned long long start_mask = ~(pair_mask << 1);
  const bool isstart = (start_mask >> lane) & 1ULL;
  const bool ispair = (pair_mask >> lane) & 1ULL;
  double fdiag = 0.0, mymod = 1e300;
  if (isstart) {
    if (ispair) {
      double a = TF(lane, lane), b = TF(lane, lane + 1);
      double c = TF(lane + 1, lane), d = TF(lane + 1, lane + 1);
      fdiag = sqrt(fmax(a * d - b * c, 0.0));
    } else {
      fdiag = fabs(TF(lane, lane));
    }
    mymod = fdiag;
  }
  #pragma unroll
  for (int off = 32; off; off >>= 1) mymod = fmin(mymod, __shfl_xor(mymod, off));
  const double cshift = 1e-6 * mymod;

  if (tid < NN) {
    int nb = (int)__popcll(start_mask & ((1ULL << lane) - 1ULL));
    bi_of[lane] = nb;  // ordinal (meaningful at start positions)
    if (isstart) blkstart[nb] = lane;
  }
  for (int r = w; r < NN; r += 4) FF(r, lane) = 0.0f;
  __syncthreads();
  if (tid < NN && isstart) {
    FF(lane, lane) = (float)fdiag;
    if (ispair) FF(lane + 1, lane + 1) = (float)fdiag;
  }
  __syncthreads();

  // ---------------- Parlett recurrence, 4 threads per pair ----------------
  const int sub = lane & 3;           // k-slice within the pair's group
  const int si = (lane & ~3) | w;     // pair row; si&3 == w balances waves

  for (int dist = 1; dist < NN; ++dist) {
    const int sj = si + dist;
    bool active = (sj < NN) && ((start_mask >> si) & 1ULL) && ((start_mask >> sj) & 1ULL);
    if (active) {
      const int p = ((pair_mask >> si) & 1ULL) ? 2 : 1;
      const int q = ((pair_mask >> sj) & 1ULL) ? 2 : 1;
      const int bi0 = bi_of[si], bi1 = bi_of[sj];
      double c00 = 0, c01 = 0, c10 = 0, c11 = 0;
      for (int b = bi0 + sub; b < bi1; b += 4) {  // k in [si, sj)
        const int k = blkstart[b];
        const bool kp = (pair_mask >> k) & 1ULL;
        double f00 = FF(si, k);
        double f01 = kp ? (double)FF(si, k + 1) : 0.0;
        double f10 = (p == 2) ? (double)FF(si + 1, k) : 0.0;
        double f11 = (p == 2 && kp) ? (double)FF(si + 1, k + 1) : 0.0;
        double t00 = TF(k, sj);
        double t01 = (q == 2) ? TF(k, sj + 1) : 0.0;
        double t10 = kp ? TF(k + 1, sj) : 0.0;
        double t11 = (kp && q == 2) ? TF(k + 1, sj + 1) : 0.0;
        c00 += f00 * t00 + f01 * t10;
        c01 += f00 * t01 + f01 * t11;
        c10 += f10 * t00 + f11 * t10;
        c11 += f10 * t01 + f11 * t11;
      }
      for (int b = bi0 + 1 + sub; b <= bi1; b += 4) {  // k in (si, sj]
        const int k = blkstart[b];
        const bool kp = (pair_mask >> k) & 1ULL;
        double t00 = TF(si, k);
        double t01 = kp ? TF(si, k + 1) : 0.0;
        double t10 = (p == 2) ? TF(si + 1, k) : 0.0;
        double t11 = (p == 2 && kp) ? TF(si + 1, k + 1) : 0.0;
        double f00 = FF(k, sj);
        double f01 = (q == 2) ? (double)FF(k, sj + 1) : 0.0;
        double f10 = kp ? (double)FF(k + 1, sj) : 0.0;
        double f11 = (kp && q == 2) ? (double)FF(k + 1, sj + 1) : 0.0;
        c00 -= t00 * f00 + t01 * f10;
        c01 -= t00 * f01 + t01 * f11;
        c10 -= t10 * f00 + t11 * f10;
        c11 -= t10 * f01 + t11 * f11;
      }
      // reduce over the 4-lane group (uniformly active within group)
      c00 += __shfl_xor(c00, 1); c00 += __shfl_xor(c00, 2);
      c01 += __shfl_xor(c01, 1); c01 += __shfl_xor(c01, 2);
      c10 += __shfl_xor(c10, 1); c10 += __shfl_xor(c10, 2);
      c11 += __shfl_xor(c11, 1); c11 += __shfl_xor(c11, 2);
      if (sub == 0) {
        // solve T_ii X - X T_jj = C
        double x00 = 0, x01 = 0, x10 = 0, x11 = 0;
        if (p == 1 && q == 1) {
          x00 = c00 / guard_d(TF(si, si) - TF(sj, sj));
        } else if (p == 2 && q == 1) {
          double t = TF(sj, sj);
          double m00 = TF(si, si) - t, m01 = TF(si, si + 1);
          double m10 = TF(si + 1, si), m11 = TF(si + 1, si + 1) - t;
          double dd = guard_d(m00 * m11 - m01 * m10);
          x00 = (m11 * c00 - m01 * c10) / dd;
          x10 = (m00 * c10 - m10 * c00) / dd;
        } else if (p == 1 && q == 2) {
          double t = TF(si, si);
          double m00 = t - TF(sj, sj), m01 = -TF(sj, sj + 1);
          double m10 = -TF(sj + 1, sj), m11 = t - TF(sj + 1, sj + 1);
          double dd = guard_d(m00 * m11 - m01 * m10);
          x00 = (c00 * m11 - c01 * m10) / dd;
          x01 = (c01 * m00 - c00 * m01) / dd;
        } else {
          double A00 = TF(si, si), A01 = TF(si, si + 1);
          double A10 = TF(si + 1, si), A11 = TF(si + 1, si + 1);
          double B00 = TF(sj, sj), B01 = TF(sj, sj + 1);
          double B10 = TF(sj + 1, sj), B11 = TF(sj + 1, sj + 1);
          double M[4][5] = {
              {A00 - B00, A01, -B10, 0.0, c00},
              {A10, A11 - B00, 0.0, -B10, c10},
              {-B01, 0.0, A00 - B11, A01, c01},
              {0.0, -B01, A10, A11 - B11, c11}};
          #pragma unroll
          for (int cc = 0; cc < 4; ++cc) {
            #pragma unroll
            for (int rr2 = cc + 1; rr2 < 4; ++rr2) {  // bubble-max partial pivot
              bool sw = fabs(M[rr2][cc]) > fabs(M[cc][cc]);
              #pragma unroll
              for (int t2 = cc; t2 < 5; ++t2) {
                double aa = M[cc][t2], bb = M[rr2][t2];
                M[cc][t2] = sw ? bb : aa;
                M[rr2][t2] = sw ? aa : bb;
              }
            }
            double inv = 1.0 / guard_d(M[cc][cc]);
            #pragma unroll
            for (int rr2 = cc + 1; rr2 < 4; ++rr2) {
              double f2 = M[rr2][cc] * inv;
              #pragma unroll
              for (int t2 = cc; t2 < 5; ++t2) M[rr2][t2] -= f2 * M[cc][t2];
            }
          }
          double z3 = M[3][4] / guard_d(M[3][3]);
          double z2 = (M[2][4] - M[2][3] * z3) / guard_d(M[2][2]);
          double z1 = (M[1][4] - M[1][3] * z3 - M[1][2] * z2) / guard_d(M[1][1]);
          double z0 = (M[0][4] - M[0][3] * z3 - M[0][2] * z2 - M[0][1] * z1) / guard_d(M[0][0]);
          x00 = z0; x10 = z1; x01 = z2; x11 = z3;
        }
        FF(si, sj) = (float)x00;
        if (q == 2) FF(si, sj + 1) = (float)x01;
        if (p == 2) {
          FF(si + 1, sj) = (float)x10;
          if (q == 2) FF(si + 1, sj + 1) = (float)x11;
        }
      }
    }
    __syncthreads();
  }

  // ---------------- symmetrize + eps shift (j striped across waves) ----------------
  {
    const int r = lane;
    for (int j = r + 1 + w; j < NN; j += 4) {
      float v = 0.5f * (FF(r, j) + FF(j, r));
      FF(r, j) = v;
      FF(j, r) = v;
    }
    if (w == 0) FF(r, r) += (float)cshift;
  }
  __syncthreads();

  // ---------------- stage Q into dead T region; out = Q Fs Q^T ----------------
  float* Qs = Tf;  // T dead after Parlett
  for (int c = w; c < NN; c += 4) Qs[lane * LDP + c] = Qg[c * NN + lane];
  __syncthreads();

  float acc[16];
  const int r0 = w * 16;  // each wave owns 16 output rows
  #pragma unroll
  for (int i = 0; i < 16; ++i) acc[i] = 0.0f;
  for (int k = 0; k < NN; ++k) {  // W = Q * Fs ; lane = column j
    float f = FF(k, lane);
    #pragma unroll
    for (int i = 0; i < 16; ++i) acc[i] += Qs[(r0 + i) * LDP + k] * f;
  }
  __syncthreads();  // all Fs reads done before W overwrites the region
  float* W = Fp;    // F dead after GEMM1
  #pragma unroll
  for (int i = 0; i < 16; ++i) W[(r0 + i) * LDP + lane] = acc[i];
  __syncthreads();

  #pragma unroll
  for (int i = 0; i < 16; ++i) acc[i] = 0.0f;
  for (int k = 0; k < NN; ++k) {  // out = W * Q^T ; lane = column j
    float qv = Qs[lane * LDP + k];
    #pragma unroll
    for (int i = 0; i < 16; ++i) acc[i] += W[(r0 + i) * LDP + k] * qv;
  }
  #pragma unroll
  for (int i = 0; i < 16; ++i) dst[(r0 + i) * NN + lane] = acc[i];

  #undef TF
  #undef FF
}

extern "C" void kernel_launch(void* const* d_in, const int* in_sizes, int n_in,
                              void* d_out, int out_size, void* d_ws, size_t ws_size,
                              hipStream_t stream) {
  const float* x = (const float*)d_in[0];
  float* out = (float*)d_out;
  float* ws = (float*)d_ws;  // nmat*64*64*4 B = 64 MB dense T handoff
  const int nmat = in_sizes[0] / (NN * NN);  // 4096
  hess64_kernel<<<nmat, 64, 0, stream>>>(x, out, ws);
  qr64_kernel<<<nmat, 64, 0, stream>>>(out, ws);
  parlett64_kernel<<<nmat, 256, 0, stream>>>(ws, out);
}